// Round 10
// baseline (4038.615 us; speedup 1.0000x reference)
//
#include <hip/hip_runtime.h>
#include <cstdint>
#include <cstddef>

#define BATCH   8
#define NPTS    8192
#define NPOINT  2048
#define NSAMPLE 64
#define K0      67      // 3 + 64 input channels
#define C2      128

// Exact-order squared distance, matching XLA/numpy: ((dx*dx + dy*dy) + dz*dz),
// separate mul/add (no FMA contraction), round-to-nearest f32.
__device__ __forceinline__ float d2e(float ax, float ay, float az,
                                     float bx, float by, float bz) {
#pragma clang fp contract(off)
  float dx = ax - bx;
  float dy = ay - by;
  float dz = az - bz;
  float t0 = dx * dx;
  float t1 = dy * dy;
  float t2 = dz * dz;
  return (t0 + t1) + t2;
}

// ---- wave64 reductions via DPP; result broadcast via readlane (uniform).
__device__ __forceinline__ float dpp_max_f32(float x) {
  int v;
  v = __builtin_amdgcn_update_dpp(__float_as_int(x), __float_as_int(x), 0xB1, 0xF, 0xF, false);
  x = fmaxf(x, __int_as_float(v));
  v = __builtin_amdgcn_update_dpp(__float_as_int(x), __float_as_int(x), 0x4E, 0xF, 0xF, false);
  x = fmaxf(x, __int_as_float(v));
  v = __builtin_amdgcn_update_dpp(__float_as_int(x), __float_as_int(x), 0x141, 0xF, 0xF, false);
  x = fmaxf(x, __int_as_float(v));
  v = __builtin_amdgcn_update_dpp(__float_as_int(x), __float_as_int(x), 0x140, 0xF, 0xF, false);
  x = fmaxf(x, __int_as_float(v));
  v = __builtin_amdgcn_update_dpp(__float_as_int(x), __float_as_int(x), 0x142, 0xA, 0xF, false);
  x = fmaxf(x, __int_as_float(v));
  v = __builtin_amdgcn_update_dpp(__float_as_int(x), __float_as_int(x), 0x143, 0xC, 0xF, false);
  x = fmaxf(x, __int_as_float(v));
  return __int_as_float(__builtin_amdgcn_readlane(__float_as_int(x), 63));
}

__device__ __forceinline__ int dpp_min_i32(int x) {
  int v;
  v = __builtin_amdgcn_update_dpp(x, x, 0xB1, 0xF, 0xF, false); x = min(x, v);
  v = __builtin_amdgcn_update_dpp(x, x, 0x4E, 0xF, 0xF, false); x = min(x, v);
  v = __builtin_amdgcn_update_dpp(x, x, 0x141, 0xF, 0xF, false); x = min(x, v);
  v = __builtin_amdgcn_update_dpp(x, x, 0x140, 0xF, 0xF, false); x = min(x, v);
  v = __builtin_amdgcn_update_dpp(x, x, 0x142, 0xA, 0xF, false); x = min(x, v);
  v = __builtin_amdgcn_update_dpp(x, x, 0x143, 0xC, 0xF, false); x = min(x, v);
  return __builtin_amdgcn_readlane(x, 63);
}

// quartile of N(0,1)
__device__ __forceinline__ int quant4(float v) {
  return (v < -0.6745f) ? 0 : (v < 0.f) ? 1 : (v < 0.6745f) ? 2 : 3;
}

// ---------------- FPS: per-lane micro-cluster prune, wave-granular skip ------
// One block/batch, 8 waves. Points counting-sorted (serpentine 4x4x4 quartile
// cells) so lane l of wave w owns 16 CONTIGUOUS sorted slots = a spatially
// tight micro-cluster; {center, certified radius rt} kept in registers.
// Per iteration: all waves min-reduce 8 u64 keys {~val, origIdx, slot} ->
// winner (gmax, slot). Each lane does a branchless cluster test
// (skip iff d2(q,c) > ((rt+sqrt(gmax))*1.0005+1e-6)^2, margins >> f32
// rounding; dd <= gmax always => skipped fmin provably no-op => dd bit-exact).
// ONE wave-uniform branch: fully-clean waves republish their cached key and
// skip the 16x(d2e+fmin)+scan+DPP body entirely. No in-loop global stores;
// winners logged to u16 LDS, batched writeback at the end.
__global__ __launch_bounds__(512) void fps_kernel(const float* __restrict__ xyz,
                                                  float* __restrict__ out_xyz,
                                                  float* __restrict__ out_inds) {
  const int b = blockIdx.x;
  const int tid = threadIdx.x;
  const int lane = tid & 63, w = tid >> 6;

  __shared__ float2 sxy[NPTS];                  // SORTED order
  __shared__ float  szl[NPTS];
  __shared__ unsigned short soi[NPTS];          // sorted slot -> orig idx
  __shared__ unsigned short sslot[NPOINT];      // winner SLOT per t
  __shared__ unsigned long long wred[2][8] __attribute__((aligned(16)));
  __shared__ int hist[64], cbase[64], ccnt[64];
  __shared__ int slot0;

  const float* xb = xyz + (size_t)b * NPTS * 3;

  if (tid < 64) { hist[tid] = 0; ccnt[tid] = 0; }
  __syncthreads();

  // --- histogram of serpentine quartile cells
  float lxx[16], lyy[16], lzz[16];
  int lc[16];
#pragma unroll
  for (int k = 0; k < 16; k++) {
    int i = tid + k * 512;
    float x = xb[i * 3 + 0], y = xb[i * 3 + 1], z = xb[i * 3 + 2];
    lxx[k] = x; lyy[k] = y; lzz[k] = z;
    int qx_ = quant4(x), qy_ = quant4(y), qz_ = quant4(z);
    int yy = (qx_ & 1) ? 3 - qy_ : qy_;
    int zz = ((qx_ ^ yy) & 1) ? 3 - qz_ : qz_;
    int cell = qx_ * 16 + yy * 4 + zz;
    lc[k] = cell;
    atomicAdd(&hist[cell], 1);
  }
  __syncthreads();
  if (tid == 0) {
    int s = 0;
    for (int c = 0; c < 64; c++) { cbase[c] = s; s += hist[c]; }
  }
  __syncthreads();
  // --- scatter into sorted arrays
#pragma unroll
  for (int k = 0; k < 16; k++) {
    int i = tid + k * 512;
    int pos = cbase[lc[k]] + atomicAdd(&ccnt[lc[k]], 1);
    sxy[pos] = make_float2(lxx[k], lyy[k]);
    szl[pos] = lzz[k];
    soi[pos] = (unsigned short)i;
    if (i == 0) slot0 = pos;
  }
  __syncthreads();

  const int s0 = slot0;
  const float2 q0xy = sxy[s0];
  const float q0x = q0xy.x, q0y = q0xy.y, q0z = szl[s0];
  if (tid == 0) sslot[0] = (unsigned short)s0;

  // --- own 16 contiguous SORTED points in registers; dd; cluster geometry
  const int base = tid * 16;
  float px[16], py[16], pz[16], dd[16];
  int oi[16];
  float ccx, ccy, ccz, crt;
  {
    float xlo = 1e30f, xhi = -1e30f, ylo = 1e30f, yhi = -1e30f, zlo = 1e30f, zhi = -1e30f;
#pragma unroll
    for (int j = 0; j < 16; j++) {
      float2 xy = sxy[base + j];
      px[j] = xy.x; py[j] = xy.y; pz[j] = szl[base + j];
      oi[j] = (int)soi[base + j];
      dd[j] = d2e(px[j], py[j], pz[j], q0x, q0y, q0z);
      xlo = fminf(xlo, px[j]); xhi = fmaxf(xhi, px[j]);
      ylo = fminf(ylo, py[j]); yhi = fmaxf(yhi, py[j]);
      zlo = fminf(zlo, pz[j]); zhi = fmaxf(zhi, pz[j]);
    }
    ccx = 0.5f * (xlo + xhi); ccy = 0.5f * (ylo + yhi); ccz = 0.5f * (zlo + zhi);
    float r2 = 0.f;
#pragma unroll
    for (int j = 0; j < 16; j++)
      r2 = fmaxf(r2, d2e(px[j], py[j], pz[j], ccx, ccy, ccz));
    crt = sqrtf(r2) * 1.0002f + 1e-6f;           // certified over-estimate
  }

  // --- initial key: tie-aware scan + DPP; key = {~val, origIdx, slot}
  unsigned long long wkey;
  {
    float bv = dd[0]; int boi = oi[0]; int bsl = base;
#pragma unroll
    for (int j = 1; j < 16; j++) {
      bool better = (dd[j] > bv) || (dd[j] == bv && oi[j] < boi);
      bv = better ? dd[j] : bv;
      boi = better ? oi[j] : boi;
      bsl = better ? base + j : bsl;
    }
    float vm = dpp_max_f32(bv);
    int ci = (bv == vm) ? boi : 0x7FFFFFFF;
    int mo = dpp_min_i32(ci);
    unsigned long long wb = __ballot(ci == mo);
    int src = (int)(__ffsll(wb) - 1);
    int wsl = __builtin_amdgcn_readlane(bsl, src);
    wkey = ((unsigned long long)(~__float_as_uint(vm)) << 32) |
           ((unsigned)mo << 16) | (unsigned)wsl;
  }
  if (lane == 0) wred[0][w] = wkey;
  __syncthreads();

  for (int t = 1; t < NPOINT; ++t) {
    // --- global winner = min of 8 wave keys (vectorized broadcast reads)
    const ulonglong2* wv = (const ulonglong2*)wred[(t - 1) & 1];
    ulonglong2 p0 = wv[0], p1 = wv[1], p2 = wv[2], p3 = wv[3];
    unsigned long long g0 = (p0.y < p0.x) ? p0.y : p0.x;
    unsigned long long g1 = (p1.y < p1.x) ? p1.y : p1.x;
    unsigned long long g2 = (p2.y < p2.x) ? p2.y : p2.x;
    unsigned long long g3 = (p3.y < p3.x) ? p3.y : p3.x;
    g0 = (g1 < g0) ? g1 : g0; g2 = (g3 < g2) ? g3 : g2;
    g0 = (g2 < g0) ? g2 : g0;
    const int nslot = (int)(g0 & 0xFFFFu);
    const float gmax = __uint_as_float(~(unsigned)(g0 >> 32));
    const float2 qxy = sxy[nslot];
    const float qx = qxy.x, qy = qxy.y, qz = szl[nslot];
    if (tid == 0) sslot[t] = (unsigned short)nslot;

    // --- branchless per-lane cluster test
    const float sg = sqrtf(gmax);
    float d2c = d2e(qx, qy, qz, ccx, ccy, ccz);
    float T = (crt + sg) * 1.0005f + 1e-6f;
    bool dirty = !(d2c > T * T);

    if (__ballot(dirty) != 0ull) {
      // --- dirty wave: unconditional update (no-op for clean lanes, provably
      //     bit-exact) + tie-aware scan + DPP reduce + key pack
      float d0 = d2e(px[0], py[0], pz[0], qx, qy, qz);
      dd[0] = fminf(dd[0], d0);
      float bv = dd[0]; int boi = oi[0]; int bsl = base;
#pragma unroll
      for (int j = 1; j < 16; j++) {
        float d = d2e(px[j], py[j], pz[j], qx, qy, qz);
        dd[j] = fminf(dd[j], d);
        bool better = (dd[j] > bv) || (dd[j] == bv && oi[j] < boi);
        bv = better ? dd[j] : bv;
        boi = better ? oi[j] : boi;
        bsl = better ? base + j : bsl;
      }
      float vm = dpp_max_f32(bv);
      int ci = (bv == vm) ? boi : 0x7FFFFFFF;
      int mo = dpp_min_i32(ci);
      unsigned long long wb = __ballot(ci == mo);
      int src = (int)(__ffsll(wb) - 1);
      int wsl = __builtin_amdgcn_readlane(bsl, src);
      wkey = ((unsigned long long)(~__float_as_uint(vm)) << 32) |
             ((unsigned)mo << 16) | (unsigned)wsl;
    }
    if (lane == 0) wred[t & 1][w] = wkey;   // clean waves republish cached key
    __syncthreads();
  }

  // --- parallel writeback: inds + xyz from recorded winner slots
  for (int t = tid; t < NPOINT; t += 512) {
    int s = (int)sslot[t];
    float2 xy = sxy[s];
    out_inds[b * NPOINT + t] = (float)soi[s];
    out_xyz[((size_t)b * NPOINT + t) * 3 + 0] = xy.x;
    out_xyz[((size_t)b * NPOINT + t) * 3 + 1] = xy.y;
    out_xyz[((size_t)b * NPOINT + t) * 3 + 2] = szl[s];
  }
}

// ---------------- prep: fold BN into per-channel consts ----------------------
// wsp floats: [0..255] A4[o]={sc0*W0x,sc0*W0y,sc0*W0z,sh0}; [256..319] sc1;
// [320..383] sh1; [384..511] sc2; [512..639] sh2; [640..703] sc0
__global__ __launch_bounds__(128) void prep_kernel(
    const float* __restrict__ W0, const float* __restrict__ g0,
    const float* __restrict__ b0, const float* __restrict__ m0,
    const float* __restrict__ v0, const float* __restrict__ g1,
    const float* __restrict__ b1, const float* __restrict__ m1,
    const float* __restrict__ v1, const float* __restrict__ g2,
    const float* __restrict__ b2, const float* __restrict__ m2,
    const float* __restrict__ v2, float* __restrict__ wsp) {
  const int tid = threadIdx.x;
  if (tid < 64) {
    float s0 = g0[tid] / sqrtf(v0[tid] + 1e-5f);
    wsp[4 * tid + 0] = s0 * W0[tid * K0 + 0];
    wsp[4 * tid + 1] = s0 * W0[tid * K0 + 1];
    wsp[4 * tid + 2] = s0 * W0[tid * K0 + 2];
    wsp[4 * tid + 3] = b0[tid] - m0[tid] * s0;
    wsp[640 + tid] = s0;
    float s1 = g1[tid] / sqrtf(v1[tid] + 1e-5f);
    wsp[256 + tid] = s1; wsp[320 + tid] = b1[tid] - m1[tid] * s1;
  }
  float s2 = g2[tid] / sqrtf(v2[tid] + 1e-5f);
  wsp[384 + tid] = s2; wsp[512 + tid] = b2[tid] - m2[tid] * s2;
}

// ---------------- zfeat: per-point L0 linear part ----------------------------
// szp[n][o] = sc0[o] * ( W0[o][0:3] . p_xyz + W0[o][3:67] . feat[:,n] )
__global__ __launch_bounds__(256) void zfeat_kernel(const float* __restrict__ xyz,
                                                    const float* __restrict__ feat,
                                                    const float* __restrict__ W0,
                                                    const float* __restrict__ wsp,
                                                    float* __restrict__ szp) {
  __shared__ float ftile[64][64];   // [c][u] - reads are wave-uniform
  __shared__ float sxyz[192];
  const int bt = blockIdx.x;        // b*128 + nt
  const int b = bt >> 7, nt = bt & 127;
  const int tid = threadIdx.x;
  const int lane = tid & 63, w = tid >> 6;

  const float* fb = feat + (size_t)b * 64 * NPTS + (size_t)nt * 64;
#pragma unroll
  for (int r = w; r < 64; r += 4)
    ftile[r][lane] = fb[(size_t)r * NPTS + lane];
  if (tid < 192)
    sxyz[tid] = xyz[((size_t)b * NPTS + (size_t)nt * 64) * 3 + tid];

  float w0x = W0[lane * K0 + 0], w0y = W0[lane * K0 + 1], w0z = W0[lane * K0 + 2];
  float wf[64];
#pragma unroll
  for (int i = 0; i < 64; i++) wf[i] = W0[lane * K0 + 3 + i];
  const float s0 = wsp[640 + lane];
  __syncthreads();

  float* ob = szp + ((size_t)b * NPTS + (size_t)nt * 64) * 64;
  for (int u = w; u < 64; u += 4) {
    float acc = w0x * sxyz[u * 3 + 0] + w0y * sxyz[u * 3 + 1] + w0z * sxyz[u * 3 + 2];
#pragma unroll
    for (int i = 0; i < 64; i++) acc = fmaf(wf[i], ftile[i][u], acc);
    ob[(size_t)u * 64 + lane] = acc * s0;
  }
}

// ---------------- ball query: one wave per query point -----------------------
__global__ __launch_bounds__(256) void ballq_kernel(const float* __restrict__ xyz,
                                                    const float* __restrict__ new_xyz,
                                                    int* __restrict__ ball) {
  const int lane = threadIdx.x & 63;
  const int q = blockIdx.x * 4 + (threadIdx.x >> 6);
  const int b = q >> 11;
  const float RR = (float)(0.4 * 0.4);
  const float cx = new_xyz[(size_t)q * 3 + 0];
  const float cy = new_xyz[(size_t)q * 3 + 1];
  const float cz = new_xyz[(size_t)q * 3 + 2];
  const float* xb = xyz + (size_t)b * NPTS * 3;
  int cnt = 0, firsti = -1;
  for (int base = 0; base < NPTS; base += 64) {
    int i = base + lane;
    float xx = xb[i * 3 + 0], yy = xb[i * 3 + 1], zz = xb[i * 3 + 2];
    float d2 = d2e(xx, yy, zz, cx, cy, cz);
    bool m = d2 < RR;
    unsigned long long mask = __ballot(m);
    if (mask) {
      if (firsti < 0) firsti = base + (__ffsll((unsigned long long)mask) - 1);
      int pos = cnt + (int)__popcll(mask & ((1ull << lane) - 1ull));
      if (m && pos < NSAMPLE) ball[(size_t)q * NSAMPLE + pos] = i;
      cnt += (int)__popcll(mask);
      if (cnt >= NSAMPLE) break;
    }
  }
  for (int s = cnt + lane; s < NSAMPLE; s += 64)
    ball[(size_t)q * NSAMPLE + s] = firsti;
}

// ---------------- MLP L1/L2 + max-pool: lane = channel, loop samples ---------
#define QPW 4
__global__ __launch_bounds__(256, 2) void mlp_kernel(
    const float* __restrict__ szp, const int* __restrict__ ball,
    const float* __restrict__ new_xyz, const float* __restrict__ W1,
    const float* __restrict__ W2, const float* __restrict__ wsp,
    float* __restrict__ out_feat) {
  __shared__ float ylds[4][64];
  __shared__ int   blds[4][64];
  const int tid = threadIdx.x;
  const int lane = tid & 63, wid = tid >> 6;

  float4 w1v[16], w2av[16], w2bv[16];
  const float4* W1r = (const float4*)(W1 + lane * 64);
  const float4* W2ar = (const float4*)(W2 + lane * 64);
  const float4* W2br = (const float4*)(W2 + (lane + 64) * 64);
#pragma unroll
  for (int i = 0; i < 16; i++) { w1v[i] = W1r[i]; w2av[i] = W2ar[i]; w2bv[i] = W2br[i]; }
  const float4 A = ((const float4*)wsp)[lane];
  const float sc1l = wsp[256 + lane], sh1l = wsp[320 + lane];
  const float sc2al = wsp[384 + lane], sh2al = wsp[512 + lane];
  const float sc2bl = wsp[448 + lane], sh2bl = wsp[576 + lane];

  for (int qi = 0; qi < QPW; qi++) {
    const int q = blockIdx.x * (4 * QPW) + qi * 4 + wid;
    const int b = q >> 11, p = q & 2047;

    const float cx = new_xyz[(size_t)q * 3 + 0];
    const float cy = new_xyz[(size_t)q * 3 + 1];
    const float cz = new_xyz[(size_t)q * 3 + 2];
    const float hc = A.w - (A.x * cx + A.y * cy + A.z * cz);

    blds[wid][lane] = ball[(size_t)q * NSAMPLE + lane];
    const float* szb = szp + (size_t)b * NPTS * 64;
    __builtin_amdgcn_s_waitcnt(0);   // vm+lgkm: blds visible to own wave

    float vA = 0.f, vB = 0.f;
    int idx0 = blds[wid][0];
    float fcur = szb[(size_t)idx0 * 64 + lane];
    const float4* yv = (const float4*)ylds[wid];

    for (int s = 0; s < NSAMPLE; s++) {
      int sn = (s < NSAMPLE - 1) ? s + 1 : s;
      int idxn = blds[wid][sn];
      float fnext = szb[(size_t)idxn * 64 + lane];

      float y0 = fmaxf(fcur + hc, 0.f);
      ylds[wid][lane] = y0;
      float a0 = 0.f, a1 = 0.f, a2 = 0.f, a3 = 0.f;
#pragma unroll
      for (int i = 0; i < 16; i++) {
        float4 y = yv[i];
        a0 = fmaf(w1v[i].x, y.x, a0);
        a1 = fmaf(w1v[i].y, y.y, a1);
        a2 = fmaf(w1v[i].z, y.z, a2);
        a3 = fmaf(w1v[i].w, y.w, a3);
      }
      float y1 = fmaxf(fmaf((a0 + a1) + (a2 + a3), sc1l, sh1l), 0.f);
      ylds[wid][lane] = y1;
      float c0 = 0.f, c1 = 0.f, c2 = 0.f, c3 = 0.f;
      float e0 = 0.f, e1 = 0.f, e2 = 0.f, e3 = 0.f;
#pragma unroll
      for (int i = 0; i < 16; i++) {
        float4 y = yv[i];
        c0 = fmaf(w2av[i].x, y.x, c0);
        c1 = fmaf(w2av[i].y, y.y, c1);
        c2 = fmaf(w2av[i].z, y.z, c2);
        c3 = fmaf(w2av[i].w, y.w, c3);
        e0 = fmaf(w2bv[i].x, y.x, e0);
        e1 = fmaf(w2bv[i].y, y.y, e1);
        e2 = fmaf(w2bv[i].z, y.z, e2);
        e3 = fmaf(w2bv[i].w, y.w, e3);
      }
      float y2a = fmaxf(fmaf((c0 + c1) + (c2 + c3), sc2al, sh2al), 0.f);
      float y2b = fmaxf(fmaf((e0 + e1) + (e2 + e3), sc2bl, sh2bl), 0.f);
      vA = fmaxf(vA, y2a);
      vB = fmaxf(vB, y2b);
      fcur = fnext;
    }
    out_feat[((size_t)b * C2 + lane) * NPOINT + p] = vA;
    out_feat[((size_t)b * C2 + lane + 64) * NPOINT + p] = vB;
  }
}

extern "C" void kernel_launch(void* const* d_in, const int* in_sizes, int n_in,
                              void* d_out, int out_size, void* d_ws, size_t ws_size,
                              hipStream_t stream) {
  const float* xyz  = (const float*)d_in[0];
  const float* feat = (const float*)d_in[1];
  const float* W0 = (const float*)d_in[2];
  const float* g0 = (const float*)d_in[3];
  const float* b0 = (const float*)d_in[4];
  const float* m0 = (const float*)d_in[5];
  const float* v0 = (const float*)d_in[6];
  const float* W1 = (const float*)d_in[7];
  const float* g1 = (const float*)d_in[8];
  const float* b1 = (const float*)d_in[9];
  const float* m1 = (const float*)d_in[10];
  const float* v1 = (const float*)d_in[11];
  const float* W2 = (const float*)d_in[12];
  const float* g2 = (const float*)d_in[13];
  const float* b2 = (const float*)d_in[14];
  const float* m2 = (const float*)d_in[15];
  const float* v2 = (const float*)d_in[16];

  float* out = (float*)d_out;
  float* out_xyz  = out;                         // (8,2048,3)   = 49152
  float* out_feat = out + 49152;                 // (8,128,2048) = 2097152
  float* out_inds = out + 49152 + 2097152;       // (8,2048)     = 16384

  int*   ball = (int*)d_ws;                                      // 4 MiB
  float* szp  = (float*)((char*)d_ws + 4194304);                 // 16.8 MiB
  float* wsp  = (float*)((char*)d_ws + 20971520);                // ~3 KiB

  hipLaunchKernelGGL(prep_kernel, dim3(1), dim3(128), 0, stream,
                     W0, g0, b0, m0, v0, g1, b1, m1, v1, g2, b2, m2, v2, wsp);
  hipLaunchKernelGGL(zfeat_kernel, dim3(BATCH * (NPTS / 64)), dim3(256), 0, stream,
                     xyz, feat, W0, wsp, szp);
  hipLaunchKernelGGL(fps_kernel, dim3(BATCH), dim3(512), 0, stream,
                     xyz, out_xyz, out_inds);
  hipLaunchKernelGGL(ballq_kernel, dim3((BATCH * NPOINT) / 4), dim3(256), 0, stream,
                     xyz, out_xyz, ball);
  hipLaunchKernelGGL(mlp_kernel, dim3((BATCH * NPOINT) / (4 * QPW)), dim3(256), 0, stream,
                     szp, ball, out_xyz, W1, W2, wsp, out_feat);
}

// Round 11
// 2714.093 us; speedup vs baseline: 1.4880x; 1.4880x over previous
//
#include <hip/hip_runtime.h>
#include <cstdint>
#include <cstddef>

#define BATCH   8
#define NPTS    8192
#define NPOINT  2048
#define NSAMPLE 64
#define K0      67      // 3 + 64 input channels
#define C2      128

// Exact-order squared distance, matching XLA/numpy: ((dx*dx + dy*dy) + dz*dz),
// separate mul/add (no FMA contraction), round-to-nearest f32.
__device__ __forceinline__ float d2e(float ax, float ay, float az,
                                     float bx, float by, float bz) {
#pragma clang fp contract(off)
  float dx = ax - bx;
  float dy = ay - by;
  float dz = az - bz;
  float t0 = dx * dx;
  float t1 = dy * dy;
  float t2 = dz * dz;
  return (t0 + t1) + t2;
}

// ---- wave64 reductions via DPP; result broadcast via readlane (uniform).
__device__ __forceinline__ float dpp_max_f32(float x) {
  int v;
  v = __builtin_amdgcn_update_dpp(__float_as_int(x), __float_as_int(x), 0xB1, 0xF, 0xF, false);
  x = fmaxf(x, __int_as_float(v));
  v = __builtin_amdgcn_update_dpp(__float_as_int(x), __float_as_int(x), 0x4E, 0xF, 0xF, false);
  x = fmaxf(x, __int_as_float(v));
  v = __builtin_amdgcn_update_dpp(__float_as_int(x), __float_as_int(x), 0x141, 0xF, 0xF, false);
  x = fmaxf(x, __int_as_float(v));
  v = __builtin_amdgcn_update_dpp(__float_as_int(x), __float_as_int(x), 0x140, 0xF, 0xF, false);
  x = fmaxf(x, __int_as_float(v));
  v = __builtin_amdgcn_update_dpp(__float_as_int(x), __float_as_int(x), 0x142, 0xA, 0xF, false);
  x = fmaxf(x, __int_as_float(v));
  v = __builtin_amdgcn_update_dpp(__float_as_int(x), __float_as_int(x), 0x143, 0xC, 0xF, false);
  x = fmaxf(x, __int_as_float(v));
  return __int_as_float(__builtin_amdgcn_readlane(__float_as_int(x), 63));
}

__device__ __forceinline__ int dpp_min_i32(int x) {
  int v;
  v = __builtin_amdgcn_update_dpp(x, x, 0xB1, 0xF, 0xF, false); x = min(x, v);
  v = __builtin_amdgcn_update_dpp(x, x, 0x4E, 0xF, 0xF, false); x = min(x, v);
  v = __builtin_amdgcn_update_dpp(x, x, 0x141, 0xF, 0xF, false); x = min(x, v);
  v = __builtin_amdgcn_update_dpp(x, x, 0x140, 0xF, 0xF, false); x = min(x, v);
  v = __builtin_amdgcn_update_dpp(x, x, 0x142, 0xA, 0xF, false); x = min(x, v);
  v = __builtin_amdgcn_update_dpp(x, x, 0x143, 0xC, 0xF, false); x = min(x, v);
  return __builtin_amdgcn_readlane(x, 63);
}

// ---------------- FPS: brute-force update, DPP reduce, 1 barrier/iter --------
// (R9 structure, measured 2014 us: VALU-issue-bound at ~86% per-active-CU.)
// Thread tid owns contiguous points [tid*16, tid*16+16): ascending (wave,
// lane, j) order makes first-index argmax tie-break = strict-> per-thread
// scan + DPP min-index + u64 key min across waves. Straight-line body, no
// branches, no in-loop global stores; batched writeback at the end.
__global__ __launch_bounds__(512) void fps_kernel(const float* __restrict__ xyz,
                                                  float* __restrict__ out_xyz,
                                                  float* __restrict__ out_inds) {
  const int b = blockIdx.x;
  const int tid = threadIdx.x;
  const int lane = tid & 63, w = tid >> 6;

  __shared__ float2 sxy[NPTS];                  // original order
  __shared__ float  szl[NPTS];
  __shared__ unsigned short sslot[NPOINT];      // winner index per t
  __shared__ unsigned long long wred[2][8] __attribute__((aligned(16)));

  const float* xb = xyz + (size_t)b * NPTS * 3;

  // --- coalesced stage to LDS
  for (int k = 0; k < 16; k++) {
    int i = tid + k * 512;
    sxy[i] = make_float2(xb[i * 3 + 0], xb[i * 3 + 1]);
    szl[i] = xb[i * 3 + 2];
  }
  __syncthreads();

  const float2 q0xy = sxy[0];
  const float q0x = q0xy.x, q0y = q0xy.y, q0z = szl[0];

  // --- own 16 contiguous points in registers, init dd
  const int base = tid * 16;
  float px[16], py[16], pz[16], dd[16];
#pragma unroll
  for (int j = 0; j < 16; j++) {
    float2 xy = sxy[base + j];
    px[j] = xy.x; py[j] = xy.y; pz[j] = szl[base + j];
    dd[j] = d2e(px[j], py[j], pz[j], q0x, q0y, q0z);
  }
  if (tid == 0) sslot[0] = 0;

  // --- initial per-thread scan (strict >, ascending j = first index) + reduce
  {
    float bv = dd[0]; int bj = base;
#pragma unroll
    for (int j = 1; j < 16; j++) {
      bool better = dd[j] > bv;
      bv = better ? dd[j] : bv;
      bj = better ? base + j : bj;
    }
    float vm = dpp_max_f32(bv);
    int ci = (bv == vm) ? bj : 0x7FFFFFFF;
    int widx = dpp_min_i32(ci);
    if (lane == 0)
      wred[0][w] = ((unsigned long long)(~__float_as_uint(vm)) << 32) | (unsigned)widx;
  }
  __syncthreads();

  for (int t = 1; t < NPOINT; ++t) {
    // --- global winner = min of 8 wave keys (vectorized broadcast reads)
    const ulonglong2* wv = (const ulonglong2*)wred[(t - 1) & 1];
    ulonglong2 p0 = wv[0], p1 = wv[1], p2 = wv[2], p3 = wv[3];
    unsigned long long g0 = (p0.y < p0.x) ? p0.y : p0.x;
    unsigned long long g1 = (p1.y < p1.x) ? p1.y : p1.x;
    unsigned long long g2 = (p2.y < p2.x) ? p2.y : p2.x;
    unsigned long long g3 = (p3.y < p3.x) ? p3.y : p3.x;
    g0 = (g1 < g0) ? g1 : g0; g2 = (g3 < g2) ? g3 : g2;
    g0 = (g2 < g0) ? g2 : g0;
    const int nxt = (int)(g0 & 0xFFFFFFFFu);
    const float2 qxy = sxy[nxt];
    const float qx = qxy.x, qy = qxy.y, qz = szl[nxt];
    if (tid == 0) sslot[t] = (unsigned short)nxt;

    // --- straight-line update + tie-aware scan (no branches)
    float d0 = d2e(px[0], py[0], pz[0], qx, qy, qz);
    dd[0] = fminf(dd[0], d0);
    float bv = dd[0]; int bj = base;
#pragma unroll
    for (int j = 1; j < 16; j++) {
      float d = d2e(px[j], py[j], pz[j], qx, qy, qz);
      dd[j] = fminf(dd[j], d);
      bool better = dd[j] > bv;
      bv = better ? dd[j] : bv;
      bj = better ? base + j : bj;
    }
    float vm = dpp_max_f32(bv);
    int ci = (bv == vm) ? bj : 0x7FFFFFFF;
    int widx = dpp_min_i32(ci);
    if (lane == 0)
      wred[t & 1][w] = ((unsigned long long)(~__float_as_uint(vm)) << 32) | (unsigned)widx;
    __syncthreads();
  }

  // --- parallel writeback: inds + xyz from recorded winner indices
  for (int t = tid; t < NPOINT; t += 512) {
    int o = (int)sslot[t];
    float2 xy = sxy[o];
    out_inds[b * NPOINT + t] = (float)o;
    out_xyz[((size_t)b * NPOINT + t) * 3 + 0] = xy.x;
    out_xyz[((size_t)b * NPOINT + t) * 3 + 1] = xy.y;
    out_xyz[((size_t)b * NPOINT + t) * 3 + 2] = szl[o];
  }
}

// ---------------- prep: fold BN into per-channel consts ----------------------
// wsp floats: [0..255] A4[o]={sc0*W0x,sc0*W0y,sc0*W0z,sh0}; [256..319] sc1;
// [320..383] sh1; [384..511] sc2; [512..639] sh2; [640..703] sc0
__global__ __launch_bounds__(128) void prep_kernel(
    const float* __restrict__ W0, const float* __restrict__ g0,
    const float* __restrict__ b0, const float* __restrict__ m0,
    const float* __restrict__ v0, const float* __restrict__ g1,
    const float* __restrict__ b1, const float* __restrict__ m1,
    const float* __restrict__ v1, const float* __restrict__ g2,
    const float* __restrict__ b2, const float* __restrict__ m2,
    const float* __restrict__ v2, float* __restrict__ wsp) {
  const int tid = threadIdx.x;
  if (tid < 64) {
    float s0 = g0[tid] / sqrtf(v0[tid] + 1e-5f);
    wsp[4 * tid + 0] = s0 * W0[tid * K0 + 0];
    wsp[4 * tid + 1] = s0 * W0[tid * K0 + 1];
    wsp[4 * tid + 2] = s0 * W0[tid * K0 + 2];
    wsp[4 * tid + 3] = b0[tid] - m0[tid] * s0;
    wsp[640 + tid] = s0;
    float s1 = g1[tid] / sqrtf(v1[tid] + 1e-5f);
    wsp[256 + tid] = s1; wsp[320 + tid] = b1[tid] - m1[tid] * s1;
  }
  float s2 = g2[tid] / sqrtf(v2[tid] + 1e-5f);
  wsp[384 + tid] = s2; wsp[512 + tid] = b2[tid] - m2[tid] * s2;
}

// ---------------- zfeat: per-point L0 linear part ----------------------------
// szp[n][o] = sc0[o] * ( W0[o][0:3] . p_xyz + W0[o][3:67] . feat[:,n] )
__global__ __launch_bounds__(256) void zfeat_kernel(const float* __restrict__ xyz,
                                                    const float* __restrict__ feat,
                                                    const float* __restrict__ W0,
                                                    const float* __restrict__ wsp,
                                                    float* __restrict__ szp) {
  __shared__ float ftile[64][64];   // [c][u] - reads are wave-uniform
  __shared__ float sxyz[192];
  const int bt = blockIdx.x;        // b*128 + nt
  const int b = bt >> 7, nt = bt & 127;
  const int tid = threadIdx.x;
  const int lane = tid & 63, w = tid >> 6;

  const float* fb = feat + (size_t)b * 64 * NPTS + (size_t)nt * 64;
#pragma unroll
  for (int r = w; r < 64; r += 4)
    ftile[r][lane] = fb[(size_t)r * NPTS + lane];
  if (tid < 192)
    sxyz[tid] = xyz[((size_t)b * NPTS + (size_t)nt * 64) * 3 + tid];

  float w0x = W0[lane * K0 + 0], w0y = W0[lane * K0 + 1], w0z = W0[lane * K0 + 2];
  float wf[64];
#pragma unroll
  for (int i = 0; i < 64; i++) wf[i] = W0[lane * K0 + 3 + i];
  const float s0 = wsp[640 + lane];
  __syncthreads();

  float* ob = szp + ((size_t)b * NPTS + (size_t)nt * 64) * 64;
  for (int u = w; u < 64; u += 4) {
    float acc = w0x * sxyz[u * 3 + 0] + w0y * sxyz[u * 3 + 1] + w0z * sxyz[u * 3 + 2];
#pragma unroll
    for (int i = 0; i < 64; i++) acc = fmaf(wf[i], ftile[i][u], acc);
    ob[(size_t)u * 64 + lane] = acc * s0;
  }
}

// ---------------- ball query: one wave per query point -----------------------
__global__ __launch_bounds__(256) void ballq_kernel(const float* __restrict__ xyz,
                                                    const float* __restrict__ new_xyz,
                                                    int* __restrict__ ball) {
  const int lane = threadIdx.x & 63;
  const int q = blockIdx.x * 4 + (threadIdx.x >> 6);
  const int b = q >> 11;
  const float RR = (float)(0.4 * 0.4);
  const float cx = new_xyz[(size_t)q * 3 + 0];
  const float cy = new_xyz[(size_t)q * 3 + 1];
  const float cz = new_xyz[(size_t)q * 3 + 2];
  const float* xb = xyz + (size_t)b * NPTS * 3;
  int cnt = 0, firsti = -1;
  for (int base = 0; base < NPTS; base += 64) {
    int i = base + lane;
    float xx = xb[i * 3 + 0], yy = xb[i * 3 + 1], zz = xb[i * 3 + 2];
    float d2 = d2e(xx, yy, zz, cx, cy, cz);
    bool m = d2 < RR;
    unsigned long long mask = __ballot(m);
    if (mask) {
      if (firsti < 0) firsti = base + (__ffsll((unsigned long long)mask) - 1);
      int pos = cnt + (int)__popcll(mask & ((1ull << lane) - 1ull));
      if (m && pos < NSAMPLE) ball[(size_t)q * NSAMPLE + pos] = i;
      cnt += (int)__popcll(mask);
      if (cnt >= NSAMPLE) break;
    }
  }
  for (int s = cnt + lane; s < NSAMPLE; s += 64)
    ball[(size_t)q * NSAMPLE + s] = firsti;
}

// ---------------- MLP L1/L2 + max-pool: lane = channel, 2 samples in flight --
// Two LDS activation rows per wave; samples s and s+1 processed with
// interleaved FMA chains so each sample's LDS write->read round trips hide
// under the other's compute. Next pair's gathers prefetched at loop top.
#define QPW 4
__global__ __launch_bounds__(256, 2) void mlp_kernel(
    const float* __restrict__ szp, const int* __restrict__ ball,
    const float* __restrict__ new_xyz, const float* __restrict__ W1,
    const float* __restrict__ W2, const float* __restrict__ wsp,
    float* __restrict__ out_feat) {
  __shared__ float ylds[4][2][64];
  __shared__ int   blds[4][64];
  const int tid = threadIdx.x;
  const int lane = tid & 63, wid = tid >> 6;

  float4 w1v[16], w2av[16], w2bv[16];
  const float4* W1r = (const float4*)(W1 + lane * 64);
  const float4* W2ar = (const float4*)(W2 + lane * 64);
  const float4* W2br = (const float4*)(W2 + (lane + 64) * 64);
#pragma unroll
  for (int i = 0; i < 16; i++) { w1v[i] = W1r[i]; w2av[i] = W2ar[i]; w2bv[i] = W2br[i]; }
  const float4 A = ((const float4*)wsp)[lane];
  const float sc1l = wsp[256 + lane], sh1l = wsp[320 + lane];
  const float sc2al = wsp[384 + lane], sh2al = wsp[512 + lane];
  const float sc2bl = wsp[448 + lane], sh2bl = wsp[576 + lane];

  float* yA = ylds[wid][0];
  float* yB = ylds[wid][1];
  const float4* yva = (const float4*)yA;
  const float4* yvb = (const float4*)yB;

  for (int qi = 0; qi < QPW; qi++) {
    const int q = blockIdx.x * (4 * QPW) + qi * 4 + wid;
    const int b = q >> 11, p = q & 2047;

    const float cx = new_xyz[(size_t)q * 3 + 0];
    const float cy = new_xyz[(size_t)q * 3 + 1];
    const float cz = new_xyz[(size_t)q * 3 + 2];
    const float hc = A.w - (A.x * cx + A.y * cy + A.z * cz);

    blds[wid][lane] = ball[(size_t)q * NSAMPLE + lane];
    const float* szb = szp + (size_t)b * NPTS * 64;
    __builtin_amdgcn_s_waitcnt(0);   // vm+lgkm: blds visible to own wave

    float vA = 0.f, vB = 0.f;        // pooled channels lane, lane+64
    int i0 = blds[wid][0], i1 = blds[wid][1];
    float fA = szb[(size_t)i0 * 64 + lane];
    float fB = szb[(size_t)i1 * 64 + lane];

    for (int s = 0; s < NSAMPLE; s += 2) {
      // prefetch next pair's channel values
      int sn0 = (s + 2 < NSAMPLE) ? s + 2 : s;
      int sn1 = (s + 3 < NSAMPLE) ? s + 3 : s;
      int in0 = blds[wid][sn0], in1 = blds[wid][sn1];
      float fn0 = szb[(size_t)in0 * 64 + lane];
      float fn1 = szb[(size_t)in1 * 64 + lane];

      // L0 epilogue, both samples
      float y0a = fmaxf(fA + hc, 0.f);
      float y0b = fmaxf(fB + hc, 0.f);
      yA[lane] = y0a;
      yB[lane] = y0b;
      // L1 both: dot(w1_row, y0) via uniform float4 broadcasts
      float a0 = 0.f, a1 = 0.f, b0_ = 0.f, b1_ = 0.f;
#pragma unroll
      for (int i = 0; i < 16; i++) {
        float4 ya = yva[i], yb = yvb[i];
        float4 wv = w1v[i];
        a0 = fmaf(wv.x, ya.x, a0); a1 = fmaf(wv.y, ya.y, a1);
        a0 = fmaf(wv.z, ya.z, a0); a1 = fmaf(wv.w, ya.w, a1);
        b0_ = fmaf(wv.x, yb.x, b0_); b1_ = fmaf(wv.y, yb.y, b1_);
        b0_ = fmaf(wv.z, yb.z, b0_); b1_ = fmaf(wv.w, yb.w, b1_);
      }
      float y1a = fmaxf(fmaf(a0 + a1, sc1l, sh1l), 0.f);
      float y1b = fmaxf(fmaf(b0_ + b1_, sc1l, sh1l), 0.f);
      yA[lane] = y1a;
      yB[lane] = y1b;
      // L2 both: two output rows per lane, shared broadcast reads
      float c0 = 0.f, c1 = 0.f, e0 = 0.f, e1 = 0.f;
      float c0b = 0.f, c1b = 0.f, e0b = 0.f, e1b = 0.f;
#pragma unroll
      for (int i = 0; i < 16; i++) {
        float4 ya = yva[i], yb = yvb[i];
        float4 wa = w2av[i], wb = w2bv[i];
        c0 = fmaf(wa.x, ya.x, c0); c1 = fmaf(wa.y, ya.y, c1);
        c0 = fmaf(wa.z, ya.z, c0); c1 = fmaf(wa.w, ya.w, c1);
        e0 = fmaf(wb.x, ya.x, e0); e1 = fmaf(wb.y, ya.y, e1);
        e0 = fmaf(wb.z, ya.z, e0); e1 = fmaf(wb.w, ya.w, e1);
        c0b = fmaf(wa.x, yb.x, c0b); c1b = fmaf(wa.y, yb.y, c1b);
        c0b = fmaf(wa.z, yb.z, c0b); c1b = fmaf(wa.w, yb.w, c1b);
        e0b = fmaf(wb.x, yb.x, e0b); e1b = fmaf(wb.y, yb.y, e1b);
        e0b = fmaf(wb.z, yb.z, e0b); e1b = fmaf(wb.w, yb.w, e1b);
      }
      float y2aA = fmaxf(fmaf(c0 + c1, sc2al, sh2al), 0.f);
      float y2bA = fmaxf(fmaf(e0 + e1, sc2bl, sh2bl), 0.f);
      float y2aB = fmaxf(fmaf(c0b + c1b, sc2al, sh2al), 0.f);
      float y2bB = fmaxf(fmaf(e0b + e1b, sc2bl, sh2bl), 0.f);
      vA = fmaxf(vA, fmaxf(y2aA, y2aB));
      vB = fmaxf(vB, fmaxf(y2bA, y2bB));
      fA = fn0;
      fB = fn1;
    }
    out_feat[((size_t)b * C2 + lane) * NPOINT + p] = vA;
    out_feat[((size_t)b * C2 + lane + 64) * NPOINT + p] = vB;
  }
}

extern "C" void kernel_launch(void* const* d_in, const int* in_sizes, int n_in,
                              void* d_out, int out_size, void* d_ws, size_t ws_size,
                              hipStream_t stream) {
  const float* xyz  = (const float*)d_in[0];
  const float* feat = (const float*)d_in[1];
  const float* W0 = (const float*)d_in[2];
  const float* g0 = (const float*)d_in[3];
  const float* b0 = (const float*)d_in[4];
  const float* m0 = (const float*)d_in[5];
  const float* v0 = (const float*)d_in[6];
  const float* W1 = (const float*)d_in[7];
  const float* g1 = (const float*)d_in[8];
  const float* b1 = (const float*)d_in[9];
  const float* m1 = (const float*)d_in[10];
  const float* v1 = (const float*)d_in[11];
  const float* W2 = (const float*)d_in[12];
  const float* g2 = (const float*)d_in[13];
  const float* b2 = (const float*)d_in[14];
  const float* m2 = (const float*)d_in[15];
  const float* v2 = (const float*)d_in[16];

  float* out = (float*)d_out;
  float* out_xyz  = out;                         // (8,2048,3)   = 49152
  float* out_feat = out + 49152;                 // (8,128,2048) = 2097152
  float* out_inds = out + 49152 + 2097152;       // (8,2048)     = 16384

  int*   ball = (int*)d_ws;                                      // 4 MiB
  float* szp  = (float*)((char*)d_ws + 4194304);                 // 16.8 MiB
  float* wsp  = (float*)((char*)d_ws + 20971520);                // ~3 KiB

  hipLaunchKernelGGL(prep_kernel, dim3(1), dim3(128), 0, stream,
                     W0, g0, b0, m0, v0, g1, b1, m1, v1, g2, b2, m2, v2, wsp);
  hipLaunchKernelGGL(zfeat_kernel, dim3(BATCH * (NPTS / 64)), dim3(256), 0, stream,
                     xyz, feat, W0, wsp, szp);
  hipLaunchKernelGGL(fps_kernel, dim3(BATCH), dim3(512), 0, stream,
                     xyz, out_xyz, out_inds);
  hipLaunchKernelGGL(ballq_kernel, dim3((BATCH * NPOINT) / 4), dim3(256), 0, stream,
                     xyz, out_xyz, ball);
  hipLaunchKernelGGL(mlp_kernel, dim3((BATCH * NPOINT) / (4 * QPW)), dim3(256), 0, stream,
                     szp, ball, out_xyz, W1, W2, wsp, out_feat);
}